// Round 2
// baseline (25334.586 us; speedup 1.0000x reference)
//
#include <hip/hip_runtime.h>

#define T_STEPS 32768
#define DIN 256
#define HID 64
#define G3 192
#define JJ 1024
#define PF 4          // gi register-prefetch depth (steps ahead)

__device__ __forceinline__ float lane_f(float v, int k) {
    return __uint_as_float(__builtin_amdgcn_readlane(__float_as_uint(v), k));
}

// ---------------- K1: gi = x @ w_ih^T + b_ih  (T x 192) ----------------
__global__ __launch_bounds__(192)
void k_gi(const float* __restrict__ states, const float* __restrict__ w_ih,
          const float* __restrict__ b_ih, float* __restrict__ gi)
{
    __shared__ __align__(16) float xs[32 * DIN];   // 32 KB x-tile
    const int tid  = threadIdx.x;
    const int row0 = blockIdx.x * 32;

    for (int i = tid; i < 32 * DIN; i += 192)
        xs[i] = states[(size_t)(row0 + (i >> 8)) * (DIN + 3) + (i & 255)];
    __syncthreads();

    const int c = tid;                 // one output column per thread
    float acc[32];
#pragma unroll
    for (int r = 0; r < 32; ++r) acc[r] = 0.f;

    for (int k4 = 0; k4 < DIN / 4; ++k4) {
        const float4 wv = *(const float4*)&w_ih[c * DIN + k4 * 4];
#pragma unroll
        for (int r = 0; r < 32; ++r) {
            const float4 xv = *(const float4*)&xs[r * DIN + k4 * 4];  // LDS broadcast
            acc[r] += xv.x * wv.x + xv.y * wv.y + xv.z * wv.z + xv.w * wv.w;
        }
    }
    const float bi = b_ih[c];
#pragma unroll
    for (int r = 0; r < 32; ++r)
        gi[(size_t)(row0 + r) * G3 + c] = acc[r] + bi;
}

// ---------------- K2: sequential GRU scan (single WAVE, no LDS, no barriers) --
// Lane t owns w_hh rows t (r-gate), t+64 (z-gate), t+128 (n-gate) in VGPRs.
// h lives lane-distributed in hv; each step it is all-gathered into SGPRs via
// v_readlane (no LDS pipe, no barrier). gi streams through a depth-PF rotating
// register buffer so global-load latency is off the critical path.
__global__ __launch_bounds__(64, 1)
void k_scan(const float* __restrict__ gi, const float* __restrict__ w_hh,
            const float* __restrict__ b_hh, const float* __restrict__ h0,
            float* __restrict__ hs, float* __restrict__ h_final)
{
    const int t = threadIdx.x;           // 0..63

    // weight rows in registers: 192 VGPRs (1 wave/SIMD -> budget ~512, no spill)
    float wr[HID], wz[HID], wn[HID];
#pragma unroll
    for (int k4 = 0; k4 < HID / 4; ++k4) {
        const float4 a = *(const float4*)&w_hh[(size_t)t * HID + k4 * 4];
        const float4 b = *(const float4*)&w_hh[(size_t)(t + 64) * HID + k4 * 4];
        const float4 c = *(const float4*)&w_hh[(size_t)(t + 128) * HID + k4 * 4];
        wr[k4*4+0] = a.x; wr[k4*4+1] = a.y; wr[k4*4+2] = a.z; wr[k4*4+3] = a.w;
        wz[k4*4+0] = b.x; wz[k4*4+1] = b.y; wz[k4*4+2] = b.z; wz[k4*4+3] = b.w;
        wn[k4*4+0] = c.x; wn[k4*4+1] = c.y; wn[k4*4+2] = c.z; wn[k4*4+3] = c.w;
    }
    const float bhr = b_hh[t];
    const float bhz = b_hh[t + 64];
    const float bhn = b_hh[t + 128];

    float hv = h0[t];

    // rotating gi prefetch (PF steps ahead)
    float pr[PF], pz[PF], pn[PF];
#pragma unroll
    for (int j = 0; j < PF; ++j) {
        pr[j] = gi[(size_t)j * G3 + t];
        pz[j] = gi[(size_t)j * G3 + 64 + t];
        pn[j] = gi[(size_t)j * G3 + 128 + t];
    }

#pragma unroll PF
    for (int s = 0; s < T_STEPS; ++s) {
        const int j = s & (PF - 1);
        const float gir = pr[j], giz = pz[j], gin = pn[j];

        // refill slot j for step s+PF (wrap keeps the address valid; values
        // loaded past the end are never consumed)
        const int sp = (s + PF) & (T_STEPS - 1);
        pr[j] = gi[(size_t)sp * G3 + t];
        pz[j] = gi[(size_t)sp * G3 + 64 + t];
        pn[j] = gi[(size_t)sp * G3 + 128 + t];

        // matvec: h all-gathered via readlane -> SGPR, FMA with SGPR operand
        float ar = bhr, az = bhz, an = bhn;
#pragma unroll
        for (int k = 0; k < HID; ++k) {
            const float hk = lane_f(hv, k);
            ar = fmaf(wr[k], hk, ar);
            az = fmaf(wz[k], hk, az);
            an = fmaf(wn[k], hk, an);
        }

        // gates (same formulas as R1 — numerics already validated)
        const float r    = 1.f / (1.f + __expf(-(ar + gir)));
        const float z    = 1.f / (1.f + __expf(-(az + giz)));
        const float npre = gin + r * an;
        const float n    = 1.f - 2.f / (__expf(2.f * npre) + 1.f);   // tanh
        hv = (1.f - z) * n + z * hv;

        hs[(size_t)s * HID + t] = hv;    // fire-and-forget, coalesced 256 B
    }
    h_final[t] = hv;
}

// ---------------- K3: logits = hs @ w_out^T + b_out, masked ----------------
__global__ __launch_bounds__(256)
void k_out(const float* __restrict__ hs, const float* __restrict__ w_out,
           const float* __restrict__ b_out, const int* __restrict__ mask,
           float* __restrict__ out)
{
    __shared__ __align__(16) float hs_s[16 * HID];
    const int tid  = threadIdx.x;
    const int row0 = blockIdx.x * 16;

    {   // stage 16 rows of hs (contiguous 1024 floats)
        const float4 v = *(const float4*)&hs[(size_t)row0 * HID + tid * 4];
        *(float4*)&hs_s[tid * 4] = v;
    }
    __syncthreads();

    float acc[16][4];
#pragma unroll
    for (int r = 0; r < 16; ++r)
#pragma unroll
        for (int cc = 0; cc < 4; ++cc) acc[r][cc] = 0.f;

    for (int k4 = 0; k4 < HID / 4; ++k4) {
        float4 wv[4];
#pragma unroll
        for (int cc = 0; cc < 4; ++cc)
            wv[cc] = *(const float4*)&w_out[(size_t)(cc * 256 + tid) * HID + k4 * 4];
#pragma unroll
        for (int r = 0; r < 16; ++r) {
            const float4 hv = *(const float4*)&hs_s[r * HID + k4 * 4];  // broadcast
#pragma unroll
            for (int cc = 0; cc < 4; ++cc)
                acc[r][cc] += hv.x * wv[cc].x + hv.y * wv[cc].y +
                              hv.z * wv[cc].z + hv.w * wv[cc].w;
        }
    }

#pragma unroll
    for (int cc = 0; cc < 4; ++cc) {
        const int c = cc * 256 + tid;
        const float bo = b_out[c];
        const int m = mask[c];
#pragma unroll
        for (int r = 0; r < 16; ++r) {
            const float v = (m == 0) ? -1e9f : (acc[r][cc] + bo);
            out[(size_t)(row0 + r) * JJ + c] = v;
        }
    }
}

// ---------------- launch ----------------
extern "C" void kernel_launch(void* const* d_in, const int* in_sizes, int n_in,
                              void* d_out, int out_size, void* d_ws, size_t ws_size,
                              hipStream_t stream)
{
    const float* states = (const float*)d_in[0];
    const float* h0     = (const float*)d_in[1];
    const float* w_ih   = (const float*)d_in[2];
    const float* w_hh   = (const float*)d_in[3];
    const float* b_ih   = (const float*)d_in[4];
    const float* b_hh   = (const float*)d_in[5];
    const float* w_out  = (const float*)d_in[6];
    const float* b_out  = (const float*)d_in[7];
    const int*   mask   = (const int*)d_in[8];

    float* out = (float*)d_out;
    float* gi  = (float*)d_ws;                         // T*192 fp32 = 25.2 MB
    float* hs  = gi + (size_t)T_STEPS * G3;            // T*64  fp32 =  8.4 MB
    float* h_final = out + (size_t)T_STEPS * JJ;       // after logits

    k_gi  <<<dim3(T_STEPS / 32), dim3(192), 0, stream>>>(states, w_ih, b_ih, gi);
    k_scan<<<dim3(1),            dim3(64),  0, stream>>>(gi, w_hh, b_hh, h0, hs, h_final);
    k_out <<<dim3(T_STEPS / 16), dim3(256), 0, stream>>>(hs, w_out, b_out, mask, out);
}

// Round 3
// 14627.943 us; speedup vs baseline: 1.7319x; 1.7319x over previous
//
#include <hip/hip_runtime.h>

#define T_STEPS 32768
#define DIN 256
#define HID 64
#define G3 192
#define JJ 1024
#define PF 4          // gi register-prefetch depth (steps ahead)

typedef float f4 __attribute__((ext_vector_type(4)));

__device__ __forceinline__ float hsum4(f4 v) { return (v.x + v.y) + (v.z + v.w); }

// ---------------- K1: gi = x @ w_ih^T + b_ih  (T x 192) ----------------
__global__ __launch_bounds__(192)
void k_gi(const float* __restrict__ states, const float* __restrict__ w_ih,
          const float* __restrict__ b_ih, float* __restrict__ gi)
{
    __shared__ __align__(16) float xs[32 * DIN];   // 32 KB x-tile
    const int tid  = threadIdx.x;
    const int row0 = blockIdx.x * 32;

    for (int i = tid; i < 32 * DIN; i += 192)
        xs[i] = states[(size_t)(row0 + (i >> 8)) * (DIN + 3) + (i & 255)];
    __syncthreads();

    const int c = tid;                 // one output column per thread
    float acc[32];
#pragma unroll
    for (int r = 0; r < 32; ++r) acc[r] = 0.f;

    for (int k4 = 0; k4 < DIN / 4; ++k4) {
        const float4 wv = *(const float4*)&w_ih[c * DIN + k4 * 4];
#pragma unroll
        for (int r = 0; r < 32; ++r) {
            const float4 xv = *(const float4*)&xs[r * DIN + k4 * 4];  // LDS broadcast
            acc[r] += xv.x * wv.x + xv.y * wv.y + xv.z * wv.z + xv.w * wv.w;
        }
    }
    const float bi = b_ih[c];
#pragma unroll
    for (int r = 0; r < 32; ++r)
        gi[(size_t)(row0 + r) * G3 + c] = acc[r] + bi;
}

// ---------------- K2: sequential GRU scan -----------------------------------
// Single wave, no barriers. Lane t owns w_hh rows t / t+64 / t+128 as 48 NAMED
// float4 SSA values (guaranteed VGPR-resident; amdgpu_waves_per_eu(1,1) gives
// the allocator the full register file). h is gathered each step via one
// ds_write + 16 broadcast ds_read_b128 (DS pipe is in-order per wave -> no
// sync needed). K-packed v_pk_fma_f32: 96 packed FMAs/step.
#define Q16(M) M(0) M(1) M(2) M(3) M(4) M(5) M(6) M(7) \
               M(8) M(9) M(10) M(11) M(12) M(13) M(14) M(15)

__global__ __launch_bounds__(64)
__attribute__((amdgpu_waves_per_eu(1, 1)))
void k_scan(const float* __restrict__ gi, const float* __restrict__ w_hh,
            const float* __restrict__ b_hh, const float* __restrict__ h0,
            float* __restrict__ hs, float* __restrict__ h_final)
{
    __shared__ __align__(64) float h_lds[HID];
    const int t = threadIdx.x;           // 0..63

    // 48 named float4 weight fragments -> 192 VGPRs, guaranteed SSA
#define DECLW(q) f4 wr##q, wz##q, wn##q;
    Q16(DECLW)
#undef DECLW
    {
        const float* r0 = w_hh + (size_t)t * HID;
        const float* r1 = w_hh + (size_t)(t + 64) * HID;
        const float* r2 = w_hh + (size_t)(t + 128) * HID;
#define LOADW(q) wr##q = *(const f4*)&r0[q * 4]; \
                 wz##q = *(const f4*)&r1[q * 4]; \
                 wn##q = *(const f4*)&r2[q * 4];
        Q16(LOADW)
#undef LOADW
    }
    const float bhr = b_hh[t];
    const float bhz = b_hh[t + 64];
    const float bhn = b_hh[t + 128];

    float hv = h0[t];
    h_lds[t] = hv;                       // in-order DS: visible to step-0 reads

    // rotating gi prefetch, PF steps ahead
    const float* gp = gi + t;
    float pr[PF], pz[PF], pn[PF];
#pragma unroll
    for (int j = 0; j < PF; ++j) {
        pr[j] = gp[(size_t)j * G3];
        pz[j] = gp[(size_t)j * G3 + 64];
        pn[j] = gp[(size_t)j * G3 + 128];
    }

    float* hsp = hs + t;

#pragma unroll PF
    for (int s = 0; s < T_STEPS; ++s) {
        const int j = s & (PF - 1);
        const float gir = pr[j], giz = pz[j], gin = pn[j];

        const int sp = (s + PF) & (T_STEPS - 1);   // wraps: address stays valid
        pr[j] = gp[(size_t)sp * G3];
        pz[j] = gp[(size_t)sp * G3 + 64];
        pn[j] = gp[(size_t)sp * G3 + 128];

        // matvec: h quads from LDS broadcast, packed FMA along K
        f4 ar4 = {0.f, 0.f, 0.f, 0.f};
        f4 az4 = {0.f, 0.f, 0.f, 0.f};
        f4 an4 = {0.f, 0.f, 0.f, 0.f};
#define MACQ(q) { const f4 hq = *(const f4*)&h_lds[q * 4];                 \
                  ar4 = __builtin_elementwise_fma(wr##q, hq, ar4);         \
                  az4 = __builtin_elementwise_fma(wz##q, hq, az4);         \
                  an4 = __builtin_elementwise_fma(wn##q, hq, an4); }
        Q16(MACQ)
#undef MACQ
        const float ar = hsum4(ar4) + bhr;
        const float az = hsum4(az4) + bhz;
        const float an = hsum4(an4) + bhn;

        // gates (formulas already validated in R1/R2)
        const float r    = 1.f / (1.f + __expf(-(ar + gir)));
        const float z    = 1.f / (1.f + __expf(-(az + giz)));
        const float npre = gin + r * an;
        const float n    = 1.f - 2.f / (__expf(2.f * npre) + 1.f);   // tanh
        hv = (1.f - z) * n + z * hv;

        h_lds[t] = hv;                    // for next step (in-order DS pipe)
        hsp[(size_t)s * HID] = hv;        // fire-and-forget, coalesced 256 B
    }
    h_final[t] = hv;
}

// ---------------- K3: logits = hs @ w_out^T + b_out, masked ----------------
__global__ __launch_bounds__(256)
void k_out(const float* __restrict__ hs, const float* __restrict__ w_out,
           const float* __restrict__ b_out, const int* __restrict__ mask,
           float* __restrict__ out)
{
    __shared__ __align__(16) float hs_s[16 * HID];
    const int tid  = threadIdx.x;
    const int row0 = blockIdx.x * 16;

    {   // stage 16 rows of hs (contiguous 1024 floats)
        const float4 v = *(const float4*)&hs[(size_t)row0 * HID + tid * 4];
        *(float4*)&hs_s[tid * 4] = v;
    }
    __syncthreads();

    float acc[16][4];
#pragma unroll
    for (int r = 0; r < 16; ++r)
#pragma unroll
        for (int cc = 0; cc < 4; ++cc) acc[r][cc] = 0.f;

    for (int k4 = 0; k4 < HID / 4; ++k4) {
        float4 wv[4];
#pragma unroll
        for (int cc = 0; cc < 4; ++cc)
            wv[cc] = *(const float4*)&w_out[(size_t)(cc * 256 + tid) * HID + k4 * 4];
#pragma unroll
        for (int r = 0; r < 16; ++r) {
            const float4 hv = *(const float4*)&hs_s[r * HID + k4 * 4];  // broadcast
#pragma unroll
            for (int cc = 0; cc < 4; ++cc)
                acc[r][cc] += hv.x * wv[cc].x + hv.y * wv[cc].y +
                              hv.z * wv[cc].z + hv.w * wv[cc].w;
        }
    }

#pragma unroll
    for (int cc = 0; cc < 4; ++cc) {
        const int c = cc * 256 + tid;
        const float bo = b_out[c];
        const int m = mask[c];
#pragma unroll
        for (int r = 0; r < 16; ++r) {
            const float v = (m == 0) ? -1e9f : (acc[r][cc] + bo);
            out[(size_t)(row0 + r) * JJ + c] = v;
        }
    }
}

// ---------------- launch ----------------
extern "C" void kernel_launch(void* const* d_in, const int* in_sizes, int n_in,
                              void* d_out, int out_size, void* d_ws, size_t ws_size,
                              hipStream_t stream)
{
    const float* states = (const float*)d_in[0];
    const float* h0     = (const float*)d_in[1];
    const float* w_ih   = (const float*)d_in[2];
    const float* w_hh   = (const float*)d_in[3];
    const float* b_ih   = (const float*)d_in[4];
    const float* b_hh   = (const float*)d_in[5];
    const float* w_out  = (const float*)d_in[6];
    const float* b_out  = (const float*)d_in[7];
    const int*   mask   = (const int*)d_in[8];

    float* out = (float*)d_out;
    float* gi  = (float*)d_ws;                         // T*192 fp32 = 25.2 MB
    float* hs  = gi + (size_t)T_STEPS * G3;            // T*64  fp32 =  8.4 MB
    float* h_final = out + (size_t)T_STEPS * JJ;       // after logits

    k_gi  <<<dim3(T_STEPS / 32), dim3(192), 0, stream>>>(states, w_ih, b_ih, gi);
    k_scan<<<dim3(1),            dim3(64),  0, stream>>>(gi, w_hh, b_hh, h0, hs, h_final);
    k_out <<<dim3(T_STEPS / 16), dim3(256), 0, stream>>>(hs, w_out, b_out, mask, out);
}